// Round 1
// baseline (410.571 us; speedup 1.0000x reference)
//
#include <hip/hip_runtime.h>
#include <cstdint>

typedef __bf16  bf16x8 __attribute__((ext_vector_type(8)));
typedef float   f32x4  __attribute__((ext_vector_type(4)));

static constexpr int N_IMG = 32, C_IN = 256, HH = 56, WW = 56, HWP = 3136;
static constexpr int K_OUT = 256, KK = 2304;          // 9 * 256
static constexpr int HP = 58;                          // padded H/W
static constexpr size_t XPAD_ELEMS = (size_t)N_IMG * HP * HP * C_IN;   // 27,553,792
static constexpr size_t OFF_XPAD  = 0;
static constexpr size_t OFF_WSGN  = OFF_XPAD + XPAD_ELEMS * 2;          // 55,107,584
static constexpr size_t OFF_MSC   = OFF_WSGN + (size_t)K_OUT * KK * 2;  // +1,179,648
static constexpr size_t OFF_ALPHA = OFF_MSC + 1024;
static constexpr size_t OFF_PART  = OFF_ALPHA + 256;

__device__ __forceinline__ void async16(const void* g, const void* l) {
    __builtin_amdgcn_global_load_lds(
        (const __attribute__((address_space(1))) uint32_t*)g,
        (__attribute__((address_space(3))) uint32_t*)l, 16, 0, 0);
}

__device__ __forceinline__ unsigned short sign_bf16_bits(float v) {
    return (v > 0.f) ? 0x3F80u : ((v < 0.f) ? 0xBF80u : 0u);
}

// ---- K1: per-(sample,chunk) sum of |x|; 32x32 blocks, 256 thr ----
__global__ __launch_bounds__(256) void k_abs_partial(const float* __restrict__ x,
                                                     float* __restrict__ part) {
    int sample = blockIdx.y, chunk = blockIdx.x, t = threadIdx.x;
    const float4* xs = (const float4*)(x + (size_t)sample * 802816 + (size_t)chunk * 25088);
    float sum = 0.f;
    for (int i = t; i < 6272; i += 256) {
        float4 v = xs[i];
        sum += fabsf(v.x) + fabsf(v.y) + fabsf(v.z) + fabsf(v.w);
    }
    #pragma unroll
    for (int off = 32; off; off >>= 1) sum += __shfl_down(sum, off, 64);
    __shared__ float ws4[4];
    if ((t & 63) == 0) ws4[t >> 6] = sum;
    __syncthreads();
    if (t == 0) part[sample * 32 + chunk] = ws4[0] + ws4[1] + ws4[2] + ws4[3];
}

// ---- K2a: alpha[32] ----
__global__ void k_alpha(const float* __restrict__ part, float* __restrict__ alpha) {
    int s = threadIdx.x;  // 32 threads
    float sum = 0.f;
    for (int i = 0; i < 32; ++i) sum += part[s * 32 + i];
    float a = 2.f * sum / 802816.f;
    alpha[s] = fmaxf(a, 1e-5f);
}

// ---- K2m: m[256] = mean|w_k| ; 256 blocks x 64 thr ----
__global__ void k_mscale(const float* __restrict__ w, float* __restrict__ msc) {
    int ko = blockIdx.x, t = threadIdx.x;
    const float* row = w + (size_t)ko * KK;
    float sum = 0.f;
    for (int i = t; i < KK; i += 64) sum += fabsf(row[i]);
    #pragma unroll
    for (int off = 32; off; off >>= 1) sum += __shfl_down(sum, off, 64);
    if (t == 0) msc[ko] = sum / 2304.f;
}

// ---- K3: wsgn[k][(r*3+s)*256+c] = sign(w[k,c,r,s]) as bf16 bits ----
__global__ __launch_bounds__(256) void k_wsign(const float* __restrict__ w,
                                               unsigned short* __restrict__ wsgn) {
    int d = blockIdx.x * 256 + threadIdx.x;           // 589,824 total
    int ko = d / KK, rem = d % KK, rs = rem >> 8, c = rem & 255;
    float v = w[((size_t)(ko * 256 + c)) * 9 + rs];
    wsgn[d] = sign_bf16_bits(v);
}

// ---- K4: xpad[n][h+1][w+1][c] = sign(x[n,c,h,w]) as bf16 bits (NHWC, halo pre-zeroed) ----
__global__ __launch_bounds__(256) void k_xpad(const float* __restrict__ x,
                                              unsigned short* __restrict__ xpad) {
    int bx = blockIdx.x;                 // 196 = 49 hw-tiles * 4 c-tiles
    int n = blockIdx.y;
    int hwt = bx % 49, ct = bx / 49;
    int hw0 = hwt * 64, c0 = ct * 64;
    int t = threadIdx.x;
    __shared__ unsigned short tile[64][65];
    int hwl = t & 63, cl0 = t >> 6;
    #pragma unroll
    for (int cc = 0; cc < 16; ++cc) {
        int cl = cl0 + cc * 4;
        float v = x[((size_t)(n * 256 + c0 + cl)) * HWP + hw0 + hwl];
        tile[cl][hwl] = sign_bf16_bits(v);
    }
    __syncthreads();
    int lane = t & 63, wv = t >> 6;
    #pragma unroll
    for (int i = 0; i < 16; ++i) {
        int hl = wv + i * 4;
        int hw = hw0 + hl, h = hw / 56, wp = hw % 56;
        xpad[(((size_t)n * HP + h + 1) * HP + (wp + 1)) * 256 + c0 + lane] = tile[lane][hl];
    }
}

// ---- K5: implicit GEMM. OUT[ko][p] = sum_kk wsgn[ko][kk] * xs[p][kk] ----
// M = k_out (2 tiles of 128), N = p = n*hw (784 tiles of 128), K = 2304 (36 steps of 64)
__global__ __launch_bounds__(256) void k_gemm(const unsigned short* __restrict__ wsgn,
                                              const unsigned short* __restrict__ xpad,
                                              const float* __restrict__ alpha,
                                              const float* __restrict__ msc,
                                              float* __restrict__ out) {
    __shared__ unsigned short Wt[128 * 64];
    __shared__ unsigned short Xt[128 * 64];
    const int t = threadIdx.x;
    const int lane = t & 63, wv = t >> 6;
    const int ntile = blockIdx.x, mtile = blockIdx.y;
    const int quad = lane >> 4, r16 = lane & 15;
    const int wm = wv & 1, wn = wv >> 1;

    // staging: lane l of wave wv, round rnd fills 16B slot (wv*4+rnd)*64 + l
    // -> row = (wv*4+rnd)*8 + (l>>3), phys colgroup = l&7,
    //    logical colgroup = (l&7) ^ (row&7) = (l&7) ^ (l>>3)   (XOR bank swizzle)
    const int lrow  = lane >> 3;
    const int lcolg = (lane & 7) ^ lrow;

    const unsigned short* wp[4];
    const unsigned short* xp[4];
    const char* ldsW[4];
    const char* ldsX[4];
    #pragma unroll
    for (int rnd = 0; rnd < 4; ++rnd) {
        int row = (wv * 4 + rnd) * 8 + lrow;          // 0..127
        wp[rnd] = wsgn + (size_t)(mtile * 128 + row) * KK + lcolg * 8;
        int p = ntile * 128 + row;
        int nimg = p / HWP, hw = p - nimg * HWP;
        int h = hw / 56, wpos = hw - h * 56;
        xp[rnd] = xpad + (((size_t)nimg * HP + h) * HP + wpos) * 256 + lcolg * 8;
        ldsW[rnd] = (const char*)&Wt[0] + (wv * 4 + rnd) * 1024;
        ldsX[rnd] = (const char*)&Xt[0] + (wv * 4 + rnd) * 1024;
    }

    f32x4 acc[4][4];
    #pragma unroll
    for (int i = 0; i < 4; ++i)
        #pragma unroll
        for (int j = 0; j < 4; ++j)
            acc[i][j] = (f32x4){0.f, 0.f, 0.f, 0.f};

    for (int kt = 0; kt < 36; ++kt) {
        int rs = kt >> 2, sub = kt & 3;
        int rr = rs / 3, ss = rs - rr * 3;
        int offX = ((rr * HP + ss) << 8) + (sub << 6);  // elements
        int offW = kt << 6;
        #pragma unroll
        for (int rnd = 0; rnd < 4; ++rnd) async16(wp[rnd] + offW, ldsW[rnd]);
        #pragma unroll
        for (int rnd = 0; rnd < 4; ++rnd) async16(xp[rnd] + offX, ldsX[rnd]);
        asm volatile("s_waitcnt vmcnt(0)" ::: "memory");
        __syncthreads();

        #pragma unroll
        for (int ks = 0; ks < 2; ++ks) {
            bf16x8 af[4], bb[4];
            #pragma unroll
            for (int i = 0; i < 4; ++i) {
                int row = wm * 64 + i * 16 + r16;
                int cg = (ks * 4 + quad) ^ (row & 7);
                af[i] = *(const bf16x8*)&Wt[row * 64 + cg * 8];
            }
            #pragma unroll
            for (int j = 0; j < 4; ++j) {
                int row = wn * 64 + j * 16 + r16;
                int cg = (ks * 4 + quad) ^ (row & 7);
                bb[j] = *(const bf16x8*)&Xt[row * 64 + cg * 8];
            }
            #pragma unroll
            for (int i = 0; i < 4; ++i)
                #pragma unroll
                for (int j = 0; j < 4; ++j)
                    acc[i][j] = __builtin_amdgcn_mfma_f32_16x16x32_bf16(af[i], bb[j], acc[i][j], 0, 0, 0);
        }
        __syncthreads();
    }

    // epilogue: D row (quad*4+reg) = ko, D col (lane&15) = p
    #pragma unroll
    for (int j = 0; j < 4; ++j) {
        int p = ntile * 128 + wn * 64 + j * 16 + r16;
        int nimg = p / HWP, hw = p - nimg * HWP;
        float av = alpha[nimg];
        float* outp = out + (size_t)nimg * K_OUT * HWP + hw;
        #pragma unroll
        for (int i = 0; i < 4; ++i) {
            int ko0 = mtile * 128 + wm * 64 + i * 16 + quad * 4;
            #pragma unroll
            for (int r = 0; r < 4; ++r) {
                int ko = ko0 + r;
                outp[(size_t)ko * HWP] = acc[i][j][r] * av * msc[ko];
            }
        }
    }
}

extern "C" void kernel_launch(void* const* d_in, const int* in_sizes, int n_in,
                              void* d_out, int out_size, void* d_ws, size_t ws_size,
                              hipStream_t stream) {
    const float* x = (const float*)d_in[0];
    const float* w = (const float*)d_in[1];
    float* out = (float*)d_out;
    char* ws = (char*)d_ws;
    unsigned short* xpad  = (unsigned short*)(ws + OFF_XPAD);
    unsigned short* wsgn  = (unsigned short*)(ws + OFF_WSGN);
    float* msc   = (float*)(ws + OFF_MSC);
    float* alpha = (float*)(ws + OFF_ALPHA);
    float* part  = (float*)(ws + OFF_PART);

    hipMemsetAsync(xpad, 0, XPAD_ELEMS * 2, stream);              // halo zeros
    k_abs_partial<<<dim3(32, 32), 256, 0, stream>>>(x, part);
    k_alpha<<<1, 32, 0, stream>>>(part, alpha);
    k_mscale<<<256, 64, 0, stream>>>(w, msc);
    k_wsign<<<2304, 256, 0, stream>>>(w, wsgn);
    k_xpad<<<dim3(196, 32), 256, 0, stream>>>(x, xpad);
    k_gemm<<<dim3(784, 2), 256, 0, stream>>>(wsgn, xpad, alpha, msc, out);
}

// Round 2
// 303.527 us; speedup vs baseline: 1.3527x; 1.3527x over previous
//
#include <hip/hip_runtime.h>
#include <cstdint>

typedef int   i32x4 __attribute__((ext_vector_type(4)));
typedef int   i32x8 __attribute__((ext_vector_type(8)));
typedef float f32x4 __attribute__((ext_vector_type(4)));

static constexpr int N_IMG = 32, HWP = 3136, KK = 2304, HP = 58;
static constexpr size_t XPAD_BYTES = (size_t)N_IMG * HP * HP * 256;   // 27,553,792
static constexpr size_t OFF_XPAD = 0;
static constexpr size_t OFF_WSGN = XPAD_BYTES;                         // +589,824
static constexpr size_t OFF_MSC  = OFF_WSGN + (size_t)256 * KK;
static constexpr size_t OFF_ACC  = OFF_MSC + 1024;

__device__ __forceinline__ void async16(const void* g, const void* l) {
    __builtin_amdgcn_global_load_lds(
        (const __attribute__((address_space(1))) uint32_t*)g,
        (__attribute__((address_space(3))) uint32_t*)l, 16, 0, 0);
}

__device__ __forceinline__ unsigned char sign_fp8(float v) {
    return (v > 0.f) ? 0x38u : ((v < 0.f) ? 0xB8u : 0u);   // e4m3: +1 / -1 / 0
}

// ---- K1: weights: signs (fp8, [ko][rs*256+c]) + msc[ko] + zero acc32 ----
__global__ __launch_bounds__(256) void k_wm(const float* __restrict__ w,
                                            unsigned char* __restrict__ wsgn,
                                            float* __restrict__ msc,
                                            float* __restrict__ acc32) {
    int ko = blockIdx.x, t = threadIdx.x;
    __shared__ unsigned char s[2304];
    __shared__ float red[4];
    float sum = 0.f;
    #pragma unroll
    for (int i = 0; i < 9; ++i) {
        float v = w[(size_t)ko * KK + i * 256 + t];   // flat e = c*9+rs order
        sum += fabsf(v);
        s[i * 256 + t] = sign_fp8(v);
    }
    #pragma unroll
    for (int off = 32; off; off >>= 1) sum += __shfl_down(sum, off, 64);
    if ((t & 63) == 0) red[t >> 6] = sum;
    __syncthreads();
    if (t == 0) msc[ko] = (red[0] + red[1] + red[2] + red[3]) * (1.f / 2304.f);
    if (ko == 0 && t < 32) acc32[t] = 0.f;
    #pragma unroll
    for (int i = 0; i < 9; ++i)                        // o = rs*256+c, rs=i, c=t
        wsgn[(size_t)ko * KK + i * 256 + t] = s[t * 9 + i];
}

// ---- K2: zero halo of xpad (only border pixels; interior written by k_xpad) ----
__global__ __launch_bounds__(256) void k_halo(unsigned char* __restrict__ xpad) {
    int n = blockIdx.y;
    int id = blockIdx.x * 256 + threadIdx.x;   // 57*256 = 14592 = 228 pos * 64
    int pos = id >> 6, j = id & 63;
    int h, w;
    if (pos < 58)       { h = 0;         w = pos; }
    else if (pos < 116) { h = 57;        w = pos - 58; }
    else if (pos < 172) { h = pos - 115; w = 0; }
    else                { h = pos - 171; w = 57; }
    *(unsigned int*)&xpad[(((size_t)n * HP + h) * HP + w) * 256 + j * 4] = 0u;
}

// ---- K3: x: signs (fp8, NHWC padded) + per-sample |x| accumulation ----
__global__ __launch_bounds__(256) void k_xpad(const float* __restrict__ x,
                                              unsigned char* __restrict__ xpad,
                                              float* __restrict__ acc32) {
    int bx = blockIdx.x, n = blockIdx.y;
    int hwt = bx % 49, ct = bx / 49;
    int hw0 = hwt * 64, c0 = ct * 64;
    int t = threadIdx.x, hwl = t & 63, cb = t >> 6;
    __shared__ unsigned char tile[64][68];
    __shared__ float red[4];
    float asum = 0.f;
    #pragma unroll
    for (int cc = 0; cc < 16; ++cc) {
        int cl = cb + cc * 4;
        float v = x[((size_t)(n * 256 + c0 + cl)) * HWP + hw0 + hwl];
        asum += fabsf(v);
        tile[hwl][cl] = sign_fp8(v);
    }
    #pragma unroll
    for (int off = 32; off; off >>= 1) asum += __shfl_down(asum, off, 64);
    if ((t & 63) == 0) red[t >> 6] = asum;
    __syncthreads();
    if (t == 0) atomicAdd(&acc32[n], red[0] + red[1] + red[2] + red[3]);
    int j = t & 15, rg = t >> 4;               // j: c-quad, rg: row in pass
    #pragma unroll
    for (int ps = 0; ps < 4; ++ps) {
        int hl = ps * 16 + rg;
        int hw = hw0 + hl, h = hw / 56, wp = hw - h * 56;
        unsigned int v4 = *(const unsigned int*)&tile[hl][4 * j];
        *(unsigned int*)&xpad[(((size_t)n * HP + h + 1) * HP + (wp + 1)) * 256 + c0 + 4 * j] = v4;
    }
}

// ---- K4: MX-fp8 implicit GEMM. M=ko (2x128), N=p (784x128), K=2304 (18x128) ----
__global__ __launch_bounds__(256) void k_gemm(const unsigned char* __restrict__ wsgn,
                                              const unsigned char* __restrict__ xpad,
                                              const float* __restrict__ acc32,
                                              const float* __restrict__ msc,
                                              float* __restrict__ out) {
    __shared__ __attribute__((aligned(16))) unsigned char Wt[128 * 128];
    __shared__ __attribute__((aligned(16))) unsigned char Xt[128 * 128];
    const int t = threadIdx.x;
    const int lane = t & 63, wv = t >> 6;
    const int mtile = blockIdx.x, ntile = blockIdx.y;
    const int quad = lane >> 4, r16 = lane & 15;
    const int wm = wv & 1, wn = wv >> 1;
    // staging: lane l fills 16B slot -> row=(slotblk*8)+(l>>3), phys cg=l&7,
    // logical cg = (l&7)^(row&7) = (l&7)^(l>>3)  (XOR swizzle, 0 conflicts in R1)
    const int lrow = lane >> 3;
    const int lcolg = (lane & 7) ^ lrow;

    const unsigned char* wp[4];
    const unsigned char* xp[4];
    unsigned char* ldsW[4];
    unsigned char* ldsX[4];
    #pragma unroll
    for (int rnd = 0; rnd < 4; ++rnd) {
        int row = (wv * 4 + rnd) * 8 + lrow;          // 0..127
        wp[rnd] = wsgn + (size_t)(mtile * 128 + row) * KK + lcolg * 16;
        int p = ntile * 128 + row;
        int nimg = p / HWP, hw = p - nimg * HWP;
        int h = hw / 56, wpos = hw - h * 56;
        xp[rnd] = xpad + (((size_t)nimg * HP + h) * HP + wpos) * 256 + lcolg * 16;
        ldsW[rnd] = Wt + (wv * 4 + rnd) * 1024;
        ldsX[rnd] = Xt + (wv * 4 + rnd) * 1024;
    }

    f32x4 acc[4][4];
    #pragma unroll
    for (int i = 0; i < 4; ++i)
        #pragma unroll
        for (int j = 0; j < 4; ++j)
            acc[i][j] = (f32x4){0.f, 0.f, 0.f, 0.f};

    for (int kt = 0; kt < 18; ++kt) {
        int rs = kt >> 1, half = kt & 1;
        int rr = rs / 3, ss = rs - rr * 3;
        int offX = (rr * HP + ss) * 256 + half * 128;  // bytes
        int offW = kt * 128;
        #pragma unroll
        for (int rnd = 0; rnd < 4; ++rnd) async16(wp[rnd] + offW, ldsW[rnd]);
        #pragma unroll
        for (int rnd = 0; rnd < 4; ++rnd) async16(xp[rnd] + offX, ldsX[rnd]);
        asm volatile("s_waitcnt vmcnt(0)" ::: "memory");
        __syncthreads();

        i32x8 a8[4], b8[4];
        #pragma unroll
        for (int i = 0; i < 4; ++i) {
            int row = wm * 64 + i * 16 + r16, sw = row & 7;
            i32x4 lo = *(const i32x4*)(Wt + row * 128 + (((quad << 1)    ) ^ sw) * 16);
            i32x4 hi = *(const i32x4*)(Wt + row * 128 + (((quad << 1) | 1) ^ sw) * 16);
            a8[i] = __builtin_shufflevector(lo, hi, 0, 1, 2, 3, 4, 5, 6, 7);
        }
        #pragma unroll
        for (int j = 0; j < 4; ++j) {
            int row = wn * 64 + j * 16 + r16, sw = row & 7;
            i32x4 lo = *(const i32x4*)(Xt + row * 128 + (((quad << 1)    ) ^ sw) * 16);
            i32x4 hi = *(const i32x4*)(Xt + row * 128 + (((quad << 1) | 1) ^ sw) * 16);
            b8[j] = __builtin_shufflevector(lo, hi, 0, 1, 2, 3, 4, 5, 6, 7);
        }
        #pragma unroll
        for (int i = 0; i < 4; ++i)
            #pragma unroll
            for (int j = 0; j < 4; ++j)
                acc[i][j] = __builtin_amdgcn_mfma_scale_f32_16x16x128_f8f6f4(
                    a8[i], b8[j], acc[i][j], 0, 0, 0, 127, 0, 127);
        __syncthreads();
    }

    // epilogue: D row (quad*4+reg)=ko, D col (lane&15)=p ; alpha from acc32
    float mscv[4][4];
    #pragma unroll
    for (int i = 0; i < 4; ++i) {
        int ko0 = mtile * 128 + wm * 64 + i * 16 + quad * 4;
        #pragma unroll
        for (int r = 0; r < 4; ++r) mscv[i][r] = msc[ko0 + r];
    }
    #pragma unroll
    for (int j = 0; j < 4; ++j) {
        int p = ntile * 128 + wn * 64 + j * 16 + r16;
        int nimg = p / HWP, hw = p - nimg * HWP;
        float av = fmaxf(acc32[nimg] * (2.f / 802816.f), 1e-5f);
        float* outp = out + (size_t)nimg * 802816 + hw;
        #pragma unroll
        for (int i = 0; i < 4; ++i) {
            int ko0 = mtile * 128 + wm * 64 + i * 16 + quad * 4;
            #pragma unroll
            for (int r = 0; r < 4; ++r)
                outp[(size_t)(ko0 + r) * HWP] = acc[i][j][r] * av * mscv[i][r];
        }
    }
}

extern "C" void kernel_launch(void* const* d_in, const int* in_sizes, int n_in,
                              void* d_out, int out_size, void* d_ws, size_t ws_size,
                              hipStream_t stream) {
    const float* x = (const float*)d_in[0];
    const float* w = (const float*)d_in[1];
    float* out = (float*)d_out;
    char* ws = (char*)d_ws;
    unsigned char* xpad = (unsigned char*)(ws + OFF_XPAD);
    unsigned char* wsgn = (unsigned char*)(ws + OFF_WSGN);
    float* msc   = (float*)(ws + OFF_MSC);
    float* acc32 = (float*)(ws + OFF_ACC);

    k_wm<<<256, 256, 0, stream>>>(w, wsgn, msc, acc32);
    k_halo<<<dim3(57, N_IMG), 256, 0, stream>>>(xpad);
    k_xpad<<<dim3(196, N_IMG), 256, 0, stream>>>(x, xpad, acc32);
    k_gemm<<<dim3(2, 784), 256, 0, stream>>>(wsgn, xpad, acc32, msc, out);
}